// Round 7
// baseline (84.732 us; speedup 1.0000x reference)
//
#include <hip/hip_runtime.h>
#include <math.h>

#define NN 384
#define NT 24              // NN/16
#define LOG2E 1.44269504088896340736f

typedef __attribute__((ext_vector_type(8))) short short8;            // 8 bf16
typedef __attribute__((ext_vector_type(4))) float v4f;               // 4 fp32
typedef __attribute__((ext_vector_type(4))) unsigned short ushort4v; // 8 B

__device__ __forceinline__ unsigned short f2bf(float f) {
    union { float f; unsigned u; } v; v.f = f;
    return (unsigned short)((v.u + 0x7FFFu + ((v.u >> 16) & 1u)) >> 16);
}
__device__ __forceinline__ float bf2f(unsigned short h) {
    union { unsigned u; float f; } v; v.u = ((unsigned)h) << 16;
    return v.f;
}

// K1: 36 blocks x 256 threads; one 64x64 tile each. Coalesced P16 stores and
// LDS-transposed coalesced PT16 stores (replaces R2's 2-byte scattered stores).
__global__ __launch_bounds__(256) void build_p_kernel(
    const int* __restrict__ adj, const float* __restrict__ dist,
    const int* __restrict__ lam_ptr,
    unsigned short* __restrict__ P16, unsigned short* __restrict__ PT16)
{
    __shared__ unsigned int T[64][65];   // [local_col][local_row], u32 to keep 4B banks
    const int b = blockIdx.x;            // 6x6 tiles of 64
    const int bi = (b / 6) * 64, bj = (b % 6) * 64;
    const int tr = threadIdx.x >> 4;     // 0..15
    const int tc = threadIdx.x & 15;     // 0..15
    const float c = -(float)(*lam_ptr) * LOG2E;   // exp(-lam*d) = exp2(c*d)

#pragma unroll
    for (int s = 0; s < 4; ++s) {
        const int gi = bi + s * 16 + tr;
        const int gj = bj + tc * 4;
        float4 d4 = *(const float4*)(dist + gi * NN + gj);
        int4   a4 = *(const int4*)(adj + gi * NN + gj);
        ushort4v h;
        h[0] = (a4.x > 0 && gi != gj + 0) ? f2bf(exp2f(c * d4.x)) : 0;
        h[1] = (a4.y > 0 && gi != gj + 1) ? f2bf(exp2f(c * d4.y)) : 0;
        h[2] = (a4.z > 0 && gi != gj + 2) ? f2bf(exp2f(c * d4.z)) : 0;
        h[3] = (a4.w > 0 && gi != gj + 3) ? f2bf(exp2f(c * d4.w)) : 0;
        *(ushort4v*)(P16 + gi * NN + gj) = h;
#pragma unroll
        for (int e = 0; e < 4; ++e) T[tc * 4 + e][s * 16 + tr] = h[e];
    }
    __syncthreads();
#pragma unroll
    for (int s = 0; s < 4; ++s) {
        const int prow = bj + s * 16 + tr;   // PT16 row = global column
        const int pcol = bi + tc * 4;
        ushort4v h;
        h[0] = (unsigned short)T[s * 16 + tr][tc * 4 + 0];
        h[1] = (unsigned short)T[s * 16 + tr][tc * 4 + 1];
        h[2] = (unsigned short)T[s * 16 + tr][tc * 4 + 2];
        h[3] = (unsigned short)T[s * 16 + tr][tc * 4 + 3];
        *(ushort4v*)(PT16 + prow * NN + pcol) = h;
    }
}

// K2: 72 blocks x 256; each wave owns a 16x32 strip (2 tiles sharing the
// A-fragment, 2 independent MFMA chains). S = P*P; V = od/(P+S) gated.
__global__ __launch_bounds__(256) void v_kernel(
    const unsigned short* __restrict__ P16, const unsigned short* __restrict__ PT16,
    const float* __restrict__ od,
    float* __restrict__ V32, unsigned short* __restrict__ V16,
    unsigned short* __restrict__ VT16)
{
    const int tid = threadIdx.x;
    const int wave = tid >> 6, lane = tid & 63;
    const int sid = blockIdx.x * 4 + wave;     // 0..287 strips
    const int i0 = (sid / 12) * 16, j0 = (sid % 12) * 32;
    const int col = lane & 15, quad = lane >> 4;

    v4f acc0 = {0.f, 0.f, 0.f, 0.f};
    v4f acc1 = {0.f, 0.f, 0.f, 0.f};
    const short8* arow = (const short8*)(P16 + (i0 + col) * NN);
    const short8* b0r  = (const short8*)(PT16 + (j0 + col) * NN);
    const short8* b1r  = (const short8*)(PT16 + (j0 + 16 + col) * NN);
#pragma unroll
    for (int k0 = 0; k0 < 12; ++k0) {
        const int o = k0 * 4 + quad;           // short8 index: k0*32+quad*8 elems
        short8 a  = arow[o];
        short8 b0 = b0r[o];
        short8 b1 = b1r[o];
        acc0 = __builtin_amdgcn_mfma_f32_16x16x32_bf16(a, b0, acc0, 0, 0, 0);
        acc1 = __builtin_amdgcn_mfma_f32_16x16x32_bf16(a, b1, acc1, 0, 0, 0);
    }
#pragma unroll
    for (int t = 0; t < 2; ++t) {
        v4f acc = t ? acc1 : acc0;
#pragma unroll
        for (int r = 0; r < 4; ++r) {
            const int i = i0 + quad * 4 + r, j = j0 + t * 16 + col;
            const int idx = i * NN + j;
            const float denom = bf2f(P16[idx]) + acc[r];
            const float o2 = od[idx];
            const float v = (i != j && o2 > 0.f && denom > 0.f) ? o2 / denom : 0.f;
            V32[idx] = v;
            const unsigned short h = f2bf(v);
            V16[idx] = h;
            VT16[j * NN + i] = h;
        }
    }
}

// K3: 72 blocks x 256; each wave a 16x32 strip (2 tiles, 4 MFMA chains,
// shared aW/aU frags): W = V*P^T, U = P^T*V; out = p_exact*(V32 + W + U).
__global__ __launch_bounds__(256) void flows_kernel(
    const unsigned short* __restrict__ P16, const unsigned short* __restrict__ PT16,
    const unsigned short* __restrict__ V16, const unsigned short* __restrict__ VT16,
    const float* __restrict__ V32, const int* __restrict__ adj,
    const float* __restrict__ dist, const int* __restrict__ lam_ptr,
    float* __restrict__ out)
{
    const int tid = threadIdx.x;
    const int wave = tid >> 6, lane = tid & 63;
    const int sid = blockIdx.x * 4 + wave;
    const int i0 = (sid / 12) * 16, j0 = (sid % 12) * 32;
    const int col = lane & 15, quad = lane >> 4;

    v4f accW0 = {0.f, 0.f, 0.f, 0.f}, accW1 = {0.f, 0.f, 0.f, 0.f};
    v4f accU0 = {0.f, 0.f, 0.f, 0.f}, accU1 = {0.f, 0.f, 0.f, 0.f};
    const short8* aWr  = (const short8*)(V16 + (i0 + col) * NN);
    const short8* aUr  = (const short8*)(PT16 + (i0 + col) * NN);
    const short8* bW0r = (const short8*)(P16 + (j0 + col) * NN);
    const short8* bW1r = (const short8*)(P16 + (j0 + 16 + col) * NN);
    const short8* bU0r = (const short8*)(VT16 + (j0 + col) * NN);
    const short8* bU1r = (const short8*)(VT16 + (j0 + 16 + col) * NN);
#pragma unroll
    for (int k0 = 0; k0 < 12; ++k0) {
        const int o = k0 * 4 + quad;
        short8 aW  = aWr[o];
        short8 aU  = aUr[o];
        short8 bW0 = bW0r[o];
        short8 bW1 = bW1r[o];
        short8 bU0 = bU0r[o];
        short8 bU1 = bU1r[o];
        accW0 = __builtin_amdgcn_mfma_f32_16x16x32_bf16(aW, bW0, accW0, 0, 0, 0);
        accW1 = __builtin_amdgcn_mfma_f32_16x16x32_bf16(aW, bW1, accW1, 0, 0, 0);
        accU0 = __builtin_amdgcn_mfma_f32_16x16x32_bf16(aU, bU0, accU0, 0, 0, 0);
        accU1 = __builtin_amdgcn_mfma_f32_16x16x32_bf16(aU, bU1, accU1, 0, 0, 0);
    }
    const float c = -(float)(*lam_ptr) * LOG2E;
#pragma unroll
    for (int t = 0; t < 2; ++t) {
        v4f accW = t ? accW1 : accW0;
        v4f accU = t ? accU1 : accU0;
#pragma unroll
        for (int r = 0; r < 4; ++r) {
            const int i = i0 + quad * 4 + r, j = j0 + t * 16 + col;
            const int idx = i * NN + j;
            const float p = (adj[idx] > 0 && i != j) ? exp2f(c * dist[idx]) : 0.f;
            out[idx] = p * (V32[idx] + accW[r] + accU[r]);
        }
    }
}

extern "C" void kernel_launch(void* const* d_in, const int* in_sizes, int n_in,
                              void* d_out, int out_size, void* d_ws, size_t ws_size,
                              hipStream_t stream) {
    const float* od   = (const float*)d_in[0];
    const int*   adj  = (const int*)d_in[1];
    const float* dist = (const float*)d_in[2];
    const int*   lam  = (const int*)d_in[3];
    // d_in[4] = capacity (unused: max_iter=1, BPR update is post-output)
    float* out = (float*)d_out;

    unsigned short* P16  = (unsigned short*)d_ws;
    unsigned short* PT16 = P16 + NN * NN;
    unsigned short* V16  = PT16 + NN * NN;
    unsigned short* VT16 = V16 + NN * NN;
    float*          V32  = (float*)(VT16 + NN * NN);

    build_p_kernel<<<36, 256, 0, stream>>>(adj, dist, lam, P16, PT16);
    v_kernel<<<72, 256, 0, stream>>>(P16, PT16, od, V32, V16, VT16);
    flows_kernel<<<72, 256, 0, stream>>>(P16, PT16, V16, VT16, V32, adj, dist, lam, out);
}